// Round 4
// baseline (104.800 us; speedup 1.0000x reference)
//
#include <hip/hip_runtime.h>
#include <hip/hip_bf16.h>
#include <math.h>

typedef __bf16 bf16x8 __attribute__((ext_vector_type(8)));
typedef float  f32x4  __attribute__((ext_vector_type(4)));

#define B_ 32
#define T_ 8192

__device__ __forceinline__ float tanh_fast(float x) {
  float ex = __expf(2.0f * x);
  return 1.0f - 2.0f / (ex + 1.0f);
}

// K0: blocks 0..15 build ptab[b][a] = (dec_feat+biases, Kc[a], v[a], 0);
//     blocks 16..23 rearrange Wk into bf16 MFMA B-fragment order.
__global__ __launch_bounds__(256) void setup_kernel(
    const float* __restrict__ dec, const float* __restrict__ b_enc,
    const float* __restrict__ W_dec, const float* __restrict__ b_dec,
    const float* __restrict__ b_cov, const float* __restrict__ Wk,
    const float* __restrict__ Kc, const float* __restrict__ vvec,
    float4* __restrict__ ptab, __bf16* __restrict__ wfrag)
{
  const int blk = blockIdx.x, tid = threadIdx.x;
  if (blk < 16) {
    const int idx = blk * 256 + tid;          // [0, 4096)
    const int b = idx >> 7, a = idx & 127;
    float acc = b_dec[a] + b_enc[a] + b_cov[a];
    for (int k = 0; k < 128; ++k)
      acc += dec[b * 128 + k] * W_dec[k * 128 + a];
    ptab[idx] = make_float4(acc, Kc[a], vvec[a], 0.f);
  } else {
    // fragment id f = (ct*4+ks)*64 + lane; element j: B[k][col]
    // k = ks*32 + (lane>>4)*8 + j, col = ct*16 + (lane&15)
    const int f = (blk - 16) * 256 + tid;     // [0, 2048)
    const int l = f & 63;
    const int rest = f >> 6;                  // ct*4 + ks
    const int ks = rest & 3, ct = rest >> 2;
    for (int j = 0; j < 8; ++j) {
      const int k = ks * 32 + (l >> 4) * 8 + j;
      const int a = ct * 16 + (l & 15);
      wfrag[f * 8 + j] = (__bf16)Wk[k * 128 + a];
    }
  }
}

// K1 (fused, wave-independent): each wave owns a 32-row chunk.
// e = v.tanh(enc@Wk + add + cov*Kc); per-chunk softmax stats;
// p = exp(e-m)*mask stored; partial context from register-held enc.
// NO LDS, NO barriers.
__global__ __launch_bounds__(256, 6) void feat_ctx_kernel(
    const float* __restrict__ enc, const float* __restrict__ cov,
    const float* __restrict__ mask,
    const __bf16* __restrict__ wfrag_g, const float4* __restrict__ ptab,
    float* __restrict__ p_out, float* __restrict__ pctx,
    float* __restrict__ mchunk, float* __restrict__ schunk)
{
  const int tid  = threadIdx.x;
  const int lane = tid & 63;
  const int w    = tid >> 6;
  const int lr   = lane & 15;
  const int lg   = lane >> 4;
  const int chunk = blockIdx.x * 4 + w;        // [0, 8192)
  const long rowbase = (long)chunk * 32;
  const int b = (int)(rowbase >> 13);

  // --- A fragments: A[row = rowbase+rt*16+lr][k = ks*32 + lg*8 + j] ---
  bf16x8 afrag[2][4];
#pragma unroll
  for (int rt = 0; rt < 2; ++rt) {
    const float* rp = enc + (rowbase + rt * 16 + lr) * 128;
#pragma unroll
    for (int ks = 0; ks < 4; ++ks) {
      const float4 f0 = *(const float4*)(rp + ks * 32 + lg * 8);
      const float4 f1 = *(const float4*)(rp + ks * 32 + lg * 8 + 4);
      bf16x8 t;
      t[0]=(__bf16)f0.x; t[1]=(__bf16)f0.y; t[2]=(__bf16)f0.z; t[3]=(__bf16)f0.w;
      t[4]=(__bf16)f1.x; t[5]=(__bf16)f1.y; t[6]=(__bf16)f1.z; t[7]=(__bf16)f1.w;
      afrag[rt][ks] = t;
    }
  }

  const float4 cvA = *(const float4*)(cov + rowbase + lg * 4);
  const float4 cvB = *(const float4*)(cov + rowbase + 16 + lg * 4);
  float cv8[2][4] = {{cvA.x, cvA.y, cvA.z, cvA.w}, {cvB.x, cvB.y, cvB.z, cvB.w}};

  // --- ct-outer MFMA + fused tanh epilogue ---
  float pacc[2][4];
#pragma unroll
  for (int rt = 0; rt < 2; ++rt)
#pragma unroll
    for (int q = 0; q < 4; ++q) pacc[rt][q] = 0.f;

  const bf16x8* wfl = (const bf16x8*)wfrag_g + lane;
#pragma unroll
  for (int ct = 0; ct < 8; ++ct) {
    bf16x8 bfr[4];
#pragma unroll
    for (int ks = 0; ks < 4; ++ks) bfr[ks] = wfl[(ct * 4 + ks) * 64];
    const float4 pk = ptab[b * 128 + ct * 16 + lr];
    f32x4 a0 = {0.f, 0.f, 0.f, 0.f};
    f32x4 a1 = {0.f, 0.f, 0.f, 0.f};
#pragma unroll
    for (int ks = 0; ks < 4; ++ks) {
      a0 = __builtin_amdgcn_mfma_f32_16x16x32_bf16(afrag[0][ks], bfr[ks], a0, 0, 0, 0);
      a1 = __builtin_amdgcn_mfma_f32_16x16x32_bf16(afrag[1][ks], bfr[ks], a1, 0, 0, 0);
    }
#pragma unroll
    for (int q = 0; q < 4; ++q) {
      const float x0 = a0[q] + pk.x + cv8[0][q] * pk.y;
      const float x1 = a1[q] + pk.x + cv8[1][q] * pk.y;
      pacc[0][q] += tanh_fast(x0) * pk.z;
      pacc[1][q] += tanh_fast(x1) * pk.z;
    }
  }

  // --- e ownership butterfly over the 16 lr lanes (8 swizzles) ---
  const bool b0 = (lr & 1), b1 = ((lr >> 1) & 1), b2 = ((lr >> 2) & 1);
  float e4[4];
#pragma unroll
  for (int m = 0; m < 4; ++m) {
    const float keep = b0 ? pacc[1][m] : pacc[0][m];
    const float send = b0 ? pacc[0][m] : pacc[1][m];
    e4[m] = keep + __shfl_xor(send, 1);
  }
  float e2[2];
#pragma unroll
  for (int m = 0; m < 2; ++m) {
    const float keep = b1 ? e4[2 + m] : e4[m];
    const float send = b1 ? e4[m] : e4[2 + m];
    e2[m] = keep + __shfl_xor(send, 2);
  }
  float eo;
  {
    const float keep = b2 ? e2[1] : e2[0];
    const float send = b2 ? e2[0] : e2[1];
    eo = keep + __shfl_xor(send, 4);
  }
  eo += __shfl_xor(eo, 8);   // lanes lr and lr+8 duplicate
  const int row_own = (lr & 1) * 16 + lg * 4 + ((lr >> 1) & 1) * 2 + ((lr >> 2) & 1);

  // per-chunk max: subgroup {1,2,4,16,32} covers all 32 rows
  float m_loc = eo;
  m_loc = fmaxf(m_loc, __shfl_xor(m_loc, 1));
  m_loc = fmaxf(m_loc, __shfl_xor(m_loc, 2));
  m_loc = fmaxf(m_loc, __shfl_xor(m_loc, 4));
  m_loc = fmaxf(m_loc, __shfl_xor(m_loc, 16));
  m_loc = fmaxf(m_loc, __shfl_xor(m_loc, 32));

  // p for owned row; subgroup-sum counts each row once
  const float p_own = __expf(eo - m_loc) * mask[rowbase + row_own];
  float ps = p_own;
  ps += __shfl_xor(ps, 1);
  ps += __shfl_xor(ps, 2);
  ps += __shfl_xor(ps, 4);
  ps += __shfl_xor(ps, 16);
  ps += __shfl_xor(ps, 32);
  if (lane == 0) { schunk[chunk] = ps; mchunk[chunk] = m_loc; }

  // p for this lane's A-rows (rt*16 + lr): pull from the owner lane
  float prow[2];
#pragma unroll
  for (int rt = 0; rt < 2; ++rt) {
    const int q = lr & 3;
    const int src = rt + ((q >> 1) << 1) + ((q & 1) << 2) + ((lr >> 2) << 4);
    prow[rt] = __shfl(p_own, src);
  }
  if (lg < 2) p_out[rowbase + lg * 16 + lr] = (lg == 0) ? prow[0] : prow[1];

  // --- partial context from register-held enc fragments ---
  float ctxp[32];
#pragma unroll
  for (int c = 0; c < 32; ++c) ctxp[c] = 0.f;
#pragma unroll
  for (int rt = 0; rt < 2; ++rt) {
    const float pr = prow[rt];
#pragma unroll
    for (int ks = 0; ks < 4; ++ks)
#pragma unroll
      for (int j = 0; j < 8; ++j)
        ctxp[ks * 8 + j] += pr * (float)afrag[rt][ks][j];
  }

  // --- ctx ownership butterfly: 16+8+4+2 = 30 swizzles ---
  const bool b3 = ((lr >> 3) & 1);
  float v16[16];
#pragma unroll
  for (int m = 0; m < 16; ++m) {
    const float keep = b0 ? ctxp[2 * m + 1] : ctxp[2 * m];
    const float send = b0 ? ctxp[2 * m] : ctxp[2 * m + 1];
    v16[m] = keep + __shfl_xor(send, 1);
  }
  float v8[8];
#pragma unroll
  for (int m = 0; m < 8; ++m) {
    const float keep = b1 ? v16[2 * m + 1] : v16[2 * m];
    const float send = b1 ? v16[2 * m] : v16[2 * m + 1];
    v8[m] = keep + __shfl_xor(send, 2);
  }
  float v4[4];
#pragma unroll
  for (int m = 0; m < 4; ++m) {
    const float keep = b2 ? v8[2 * m + 1] : v8[2 * m];
    const float send = b2 ? v8[2 * m] : v8[2 * m + 1];
    v4[m] = keep + __shfl_xor(send, 4);
  }
  float v2[2];
#pragma unroll
  for (int m = 0; m < 2; ++m) {
    const float keep = b3 ? v4[2 * m + 1] : v4[2 * m];
    const float send = b3 ? v4[2 * m] : v4[2 * m + 1];
    v2[m] = keep + __shfl_xor(send, 8);
  }
  // lane lr owns c = lr and c = 16+lr; v = (c>>3)*32 + lg*8 + (c&7)
#pragma unroll
  for (int m = 0; m < 2; ++m) {
    const int c = 16 * m + lr;
    const int v = (c >> 3) * 32 + lg * 8 + (c & 7);
    pctx[(long)chunk * 128 + v] = v2[m];
  }
}

// K2: per-batch combine of 256 chunk-partials -> ctx, alpha table.
__global__ __launch_bounds__(1024) void reduce_kernel(
    const float* __restrict__ mchunk, const float* __restrict__ schunk,
    const float* __restrict__ pctx, float* __restrict__ alpha,
    float* __restrict__ ctx)
{
  const int b = blockIdx.x, tid = threadIdx.x;
  __shared__ float sm[256], al[256], red[8], part[8][128];
  float mi = 0.f, si = 0.f;
  if (tid < 256) {
    mi = mchunk[b * 256 + tid];
    si = schunk[b * 256 + tid];
    float m = mi;
#pragma unroll
    for (int off = 32; off > 0; off >>= 1) m = fmaxf(m, __shfl_xor(m, off));
    if ((tid & 63) == 0) red[tid >> 6] = m;
  }
  __syncthreads();
  const float m_all = fmaxf(fmaxf(red[0], red[1]), fmaxf(red[2], red[3]));
  if (tid < 256) {
    const float a = __expf(mi - m_all);
    sm[tid] = a;
    float z = si * a;
#pragma unroll
    for (int off = 32; off > 0; off >>= 1) z += __shfl_xor(z, off);
    if ((tid & 63) == 0) red[4 + (tid >> 6)] = z;
  }
  __syncthreads();
  const float Z = red[4] + red[5] + red[6] + red[7];
  if (tid < 256) {
    const float ai = sm[tid] / Z;
    al[tid] = ai;
    alpha[b * 256 + tid] = ai;
  }
  __syncthreads();
  const int v = tid & 127, ch = tid >> 7;
  float acc = 0.f;
#pragma unroll
  for (int k = 0; k < 32; ++k) {
    const int i = ch * 32 + k;
    acc += pctx[(long)(b * 256 + i) * 128 + v] * al[i];
  }
  part[ch][v] = acc;
  __syncthreads();
  if (tid < 128) {
    float s = 0.f;
#pragma unroll
    for (int c = 0; c < 8; ++c) s += part[c][tid];
    ctx[b * 128 + tid] = s;
  }
}

// K3: attn = p * alpha[chunk]; covout = cov + attn.
__global__ __launch_bounds__(256) void finish_kernel(
    const float* __restrict__ p_buf, const float* __restrict__ alpha,
    const float* __restrict__ cov, float* __restrict__ attn,
    float* __restrict__ covout)
{
  const long idx = (long)blockIdx.x * 256 + threadIdx.x;   // [0, 262144)
  const float a = p_buf[idx] * alpha[idx >> 5];
  attn[idx] = a;
  covout[idx] = cov[idx] + a;
}

extern "C" void kernel_launch(void* const* d_in, const int* in_sizes, int n_in,
                              void* d_out, int out_size, void* d_ws, size_t ws_size,
                              hipStream_t stream) {
  const float* enc   = (const float*)d_in[0];
  const float* dec   = (const float*)d_in[1];
  const float* mask  = (const float*)d_in[2];
  const float* cov   = (const float*)d_in[3];
  const float* Wk    = (const float*)d_in[4];
  const float* b_enc = (const float*)d_in[5];
  const float* W_dec = (const float*)d_in[6];
  const float* b_dec = (const float*)d_in[7];
  const float* Kc    = (const float*)d_in[8];
  const float* b_cov = (const float*)d_in[9];
  const float* vvec  = (const float*)d_in[10];

  float* out    = (float*)d_out;
  float* ctx    = out;                  // B*A      = 4096
  float* attn   = out + B_ * 128;       // B*T      = 262144
  float* covout = attn + B_ * T_;       // B*T      = 262144

  char* ws = (char*)d_ws;
  __bf16* wfrag  = (__bf16*)ws;                          // 32 KB
  float4* ptab   = (float4*)(ws + 32768);                // 64 KB
  float*  p_buf  = (float*)(ws + 131072);                // 1 MB
  float*  pctx   = (float*)(ws + 131072 + 1048576);      // 4 MB
  float*  mchunk = (float*)(ws + 131072 + 5242880);      // 32 KB
  float*  schunk = (float*)(ws + 131072 + 5275648);      // 32 KB
  float*  alpha  = (float*)(ws + 131072 + 5308416);      // 32 KB

  setup_kernel   <<<24,   256, 0, stream>>>(dec, b_enc, W_dec, b_dec, b_cov, Wk,
                                            Kc, vvec, ptab, wfrag);
  feat_ctx_kernel<<<2048, 256, 0, stream>>>(enc, cov, mask, wfrag, ptab,
                                            p_buf, pctx, mchunk, schunk);
  reduce_kernel  <<<32,  1024, 0, stream>>>(mchunk, schunk, pctx, alpha, ctx);
  finish_kernel  <<<1024, 256, 0, stream>>>(p_buf, alpha, cov, attn, covout);
}

// Round 5
// 67.130 us; speedup vs baseline: 1.5611x; 1.5611x over previous
//
#include <hip/hip_runtime.h>
#include <hip/hip_bf16.h>
#include <math.h>

typedef __bf16 bf16x8 __attribute__((ext_vector_type(8)));
typedef float  f32x4  __attribute__((ext_vector_type(4)));

#define B_ 32
#define T_ 8192

__device__ __forceinline__ float tanh_fast(float x) {
  float ex = __expf(2.0f * x);
  return 1.0f - 2.0f / (ex + 1.0f);
}

// K0: blocks 0..15 compute add[b][a] = dec_feat + b_dec + b_enc + b_cov;
//     blocks 16..23 rearrange Wk into bf16 MFMA B-fragment order.
__global__ __launch_bounds__(256) void setup_kernel(
    const float* __restrict__ dec, const float* __restrict__ b_enc,
    const float* __restrict__ W_dec, const float* __restrict__ b_dec,
    const float* __restrict__ b_cov, const float* __restrict__ Wk,
    float* __restrict__ addbuf, __bf16* __restrict__ wfrag)
{
  const int blk = blockIdx.x, tid = threadIdx.x;
  if (blk < 16) {
    const int idx = blk * 256 + tid;          // [0, 4096)
    const int b = idx >> 7, a = idx & 127;
    float acc = b_dec[a] + b_enc[a] + b_cov[a];
    for (int k = 0; k < 128; ++k)
      acc += dec[b * 128 + k] * W_dec[k * 128 + a];
    addbuf[idx] = acc;
  } else {
    // fragment id f = (ct*4+ks)*64 + lane; element j: B[k][col]
    // k = ks*32 + (lane>>4)*8 + j, col = ct*16 + (lane&15)
    const int f = (blk - 16) * 256 + tid;     // [0, 2048)
    const int l = f & 63;
    const int rest = f >> 6;                  // ct*4 + ks
    const int ks = rest & 3, ct = rest >> 2;
    for (int j = 0; j < 8; ++j) {
      const int k = ks * 32 + (l >> 4) * 8 + j;
      const int a = ct * 16 + (l & 15);
      wfrag[f * 8 + j] = (__bf16)Wk[k * 128 + a];
    }
  }
}

// K1: e = v.tanh(enc@Wk + add + cov*Kc); per-32-row-chunk softmax stats;
// p = exp(e - m_chunk)*mask stored. R2's proven skeleton, ctx machinery
// removed; per-wave stats (no cross-wave coupling beyond wfrag staging).
__global__ __launch_bounds__(256, 4) void feat_kernel(
    const float* __restrict__ enc, const float* __restrict__ cov,
    const float* __restrict__ mask,
    const __bf16* __restrict__ wfrag_g, const float* __restrict__ addbuf,
    const float* __restrict__ Kc, const float* __restrict__ vvec,
    float* __restrict__ p_out, float* __restrict__ mchunk,
    float* __restrict__ schunk)
{
  __shared__ __align__(16) float smem[8192];   // 32KB wfrag
  const int tid  = threadIdx.x;
  const int lane = tid & 63;
  const int w    = tid >> 6;
  const int lr   = lane & 15;
  const int lg   = lane >> 4;
  const int chunk = blockIdx.x * 4 + w;        // [0, 8192)
  const long rowbase = (long)chunk * 32;
  const int b = (int)(rowbase >> 13);

  // --- stage wfrag into LDS (coalesced) ---
  {
    const float4* src = (const float4*)wfrag_g;
    float4* dst = (float4*)smem;
#pragma unroll
    for (int i = 0; i < 8; ++i) dst[tid + i * 256] = src[tid + i * 256];
  }

  // --- A fragments: A[row = rowbase+rt*16+lr][k = ks*32 + lg*8 + j] ---
  bf16x8 afrag[2][4];
#pragma unroll
  for (int rt = 0; rt < 2; ++rt) {
    const float* rp = enc + (rowbase + rt * 16 + lr) * 128;
#pragma unroll
    for (int ks = 0; ks < 4; ++ks) {
      const float4 f0 = *(const float4*)(rp + ks * 32 + lg * 8);
      const float4 f1 = *(const float4*)(rp + ks * 32 + lg * 8 + 4);
      bf16x8 t;
      t[0]=(__bf16)f0.x; t[1]=(__bf16)f0.y; t[2]=(__bf16)f0.z; t[3]=(__bf16)f0.w;
      t[4]=(__bf16)f1.x; t[5]=(__bf16)f1.y; t[6]=(__bf16)f1.z; t[7]=(__bf16)f1.w;
      afrag[rt][ks] = t;
    }
  }

  const float4 cvA = *(const float4*)(cov + rowbase + lg * 4);
  const float4 cvB = *(const float4*)(cov + rowbase + 16 + lg * 4);
  float cv8[2][4] = {{cvA.x, cvA.y, cvA.z, cvA.w}, {cvB.x, cvB.y, cvB.z, cvB.w}};

  __syncthreads();   // wfrag staged

  // --- ct-outer MFMA + fused tanh epilogue ---
  float pacc[2][4];
#pragma unroll
  for (int rt = 0; rt < 2; ++rt)
#pragma unroll
    for (int q = 0; q < 4; ++q) pacc[rt][q] = 0.f;

  const bf16x8* wf = (const bf16x8*)smem;
#pragma unroll
  for (int ct = 0; ct < 8; ++ct) {
    bf16x8 bfr[4];
#pragma unroll
    for (int ks = 0; ks < 4; ++ks) bfr[ks] = wf[(ct * 4 + ks) * 64 + lane];
    const int col = ct * 16 + lr;
    const float addc = addbuf[b * 128 + col];
    const float kcc  = Kc[col];
    const float vc   = vvec[col];
    f32x4 a0 = {0.f, 0.f, 0.f, 0.f};
    f32x4 a1 = {0.f, 0.f, 0.f, 0.f};
#pragma unroll
    for (int ks = 0; ks < 4; ++ks) {
      a0 = __builtin_amdgcn_mfma_f32_16x16x32_bf16(afrag[0][ks], bfr[ks], a0, 0, 0, 0);
      a1 = __builtin_amdgcn_mfma_f32_16x16x32_bf16(afrag[1][ks], bfr[ks], a1, 0, 0, 0);
    }
#pragma unroll
    for (int q = 0; q < 4; ++q) {
      const float x0 = a0[q] + addc + cv8[0][q] * kcc;
      const float x1 = a1[q] + addc + cv8[1][q] * kcc;
      pacc[0][q] += tanh_fast(x0) * vc;
      pacc[1][q] += tanh_fast(x1) * vc;
    }
  }

  // --- e: reduce over the 16 lr lanes; row = rt*16 + lg*4 + q ---
  float e8[2][4];
#pragma unroll
  for (int rt = 0; rt < 2; ++rt)
#pragma unroll
    for (int q = 0; q < 4; ++q) {
      float p = pacc[rt][q];
      p += __shfl_xor(p, 1); p += __shfl_xor(p, 2);
      p += __shfl_xor(p, 4); p += __shfl_xor(p, 8);
      e8[rt][q] = p;
    }

  // chunk max: local 8 + lg-crossing shuffles (rows duplicated over lr)
  float m_loc = e8[0][0];
#pragma unroll
  for (int rt = 0; rt < 2; ++rt)
#pragma unroll
    for (int q = 0; q < 4; ++q) m_loc = fmaxf(m_loc, e8[rt][q]);
  m_loc = fmaxf(m_loc, __shfl_xor(m_loc, 16));
  m_loc = fmaxf(m_loc, __shfl_xor(m_loc, 32));

  // p = exp(e - m_loc)*mask; chunk sum = local 8 + lg-crossing (no dupes)
  float p8[2][4];
  float ps = 0.f;
#pragma unroll
  for (int rt = 0; rt < 2; ++rt)
#pragma unroll
    for (int q = 0; q < 4; ++q) {
      const float mk = mask[rowbase + rt * 16 + lg * 4 + q];
      const float pv = __expf(e8[rt][q] - m_loc) * mk;
      p8[rt][q] = pv; ps += pv;
    }
  ps += __shfl_xor(ps, 16);
  ps += __shfl_xor(ps, 32);
  if (lane == 0) { schunk[chunk] = ps; mchunk[chunk] = m_loc; }

  // p for rows rt*16 + lr via select + shfl; coalesced 32-row store
  float prow[2];
#pragma unroll
  for (int rt = 0; rt < 2; ++rt) {
    const int r3 = lr & 3;
    float sel = p8[rt][0];
    sel = (r3 == 1) ? p8[rt][1] : sel;
    sel = (r3 == 2) ? p8[rt][2] : sel;
    sel = (r3 == 3) ? p8[rt][3] : sel;
    prow[rt] = __shfl(sel, ((lr >> 2) << 4) | lr);
  }
  if (lg < 2) p_out[rowbase + lg * 16 + lr] = (lg == 0) ? prow[0] : prow[1];
}

// K2: per-batch stats combine -> alpha; zero ctx for K3's atomics.
__global__ __launch_bounds__(256) void alpha_kernel(
    const float* __restrict__ mchunk, const float* __restrict__ schunk,
    float* __restrict__ alpha, float* __restrict__ ctx)
{
  const int b = blockIdx.x, tid = threadIdx.x;
  __shared__ float red[8];
  const float mi = mchunk[b * 256 + tid];
  const float si = schunk[b * 256 + tid];
  float m = mi;
#pragma unroll
  for (int off = 32; off > 0; off >>= 1) m = fmaxf(m, __shfl_xor(m, off));
  if ((tid & 63) == 0) red[tid >> 6] = m;
  __syncthreads();
  const float m_all = fmaxf(fmaxf(red[0], red[1]), fmaxf(red[2], red[3]));
  const float a = __expf(mi - m_all);
  float z = si * a;
#pragma unroll
  for (int off = 32; off > 0; off >>= 1) z += __shfl_xor(z, off);
  if ((tid & 63) == 0) red[4 + (tid >> 6)] = z;
  __syncthreads();
  const float Z = red[4] + red[5] + red[6] + red[7];
  alpha[b * 256 + tid] = a / Z;
  if (tid < 128) ctx[b * 128 + tid] = 0.f;
}

// K3: attn = p*alpha; covout = cov + attn; ctx[b][v] += sum_t attn*enc.
// enc is L3-resident after K1 -> this pass is Infinity-Cache-bound.
__global__ __launch_bounds__(256) void ctx_attn_kernel(
    const float* __restrict__ enc, const float* __restrict__ p_buf,
    const float* __restrict__ alpha, const float* __restrict__ cov,
    float* __restrict__ attn, float* __restrict__ covout,
    float* __restrict__ ctx)
{
  const int b  = blockIdx.x >> 6;
  const int sp = blockIdx.x & 63;
  const int tid = threadIdx.x;
  const long rowbase = (long)b * T_ + sp * 128;
  __shared__ float av[128];
  __shared__ float sd[4][128];
  if (tid < 128) {
    const long r = rowbase + tid;
    const float a = p_buf[r] * alpha[r >> 5];
    attn[r] = a;
    covout[r] = cov[r] + a;
    av[tid] = a;
  }
  __syncthreads();
  const int cp = tid & 63;     // column pair (2 floats)
  const int rg = tid >> 6;     // row group
  const float* ep = enc + rowbase * 128 + cp * 2;
  float2 acc = make_float2(0.f, 0.f);
#pragma unroll 8
  for (int i = 0; i < 32; ++i) {
    const int r = i * 4 + rg;
    const float wgt = av[r];                       // LDS broadcast
    const float2 ev = *(const float2*)(ep + (long)r * 128);
    acc.x += wgt * ev.x;
    acc.y += wgt * ev.y;
  }
  ((float2*)sd[rg])[cp] = acc;
  __syncthreads();
  if (tid < 128) {
    const float s = sd[0][tid] + sd[1][tid] + sd[2][tid] + sd[3][tid];
    atomicAdd(&ctx[b * 128 + tid], s);
  }
}

extern "C" void kernel_launch(void* const* d_in, const int* in_sizes, int n_in,
                              void* d_out, int out_size, void* d_ws, size_t ws_size,
                              hipStream_t stream) {
  const float* enc   = (const float*)d_in[0];
  const float* dec   = (const float*)d_in[1];
  const float* mask  = (const float*)d_in[2];
  const float* cov   = (const float*)d_in[3];
  const float* Wk    = (const float*)d_in[4];
  const float* b_enc = (const float*)d_in[5];
  const float* W_dec = (const float*)d_in[6];
  const float* b_dec = (const float*)d_in[7];
  const float* Kc    = (const float*)d_in[8];
  const float* b_cov = (const float*)d_in[9];
  const float* vvec  = (const float*)d_in[10];

  float* out    = (float*)d_out;
  float* ctx    = out;                  // B*A      = 4096
  float* attn   = out + B_ * 128;       // B*T      = 262144
  float* covout = attn + B_ * T_;       // B*T      = 262144

  char* ws = (char*)d_ws;
  __bf16* wfrag  = (__bf16*)ws;                          // 32 KB
  float*  addbuf = (float*)(ws + 32768);                 // 16 KB
  float*  p_buf  = (float*)(ws + 49152);                 // 1 MB
  float*  mchunk = (float*)(ws + 49152 + 1048576);       // 32 KB
  float*  schunk = (float*)(ws + 49152 + 1081344);       // 32 KB
  float*  alpha  = (float*)(ws + 49152 + 1114112);       // 32 KB

  setup_kernel   <<<24,   256, 0, stream>>>(dec, b_enc, W_dec, b_dec, b_cov, Wk,
                                            addbuf, wfrag);
  feat_kernel    <<<2048, 256, 0, stream>>>(enc, cov, mask, wfrag, addbuf, Kc, vvec,
                                            p_buf, mchunk, schunk);
  alpha_kernel   <<<32,   256, 0, stream>>>(mchunk, schunk, alpha, ctx);
  ctx_attn_kernel<<<2048, 256, 0, stream>>>(enc, p_buf, alpha, cov,
                                            attn, covout, ctx);
}